// Round 18
// baseline (115.092 us; speedup 1.0000x reference)
//
#include <hip/hip_runtime.h>
#include <cstdint>
#include <cstddef>

#define NPTS 8192
#define DF   512
#define NCLS 128
#define MAXM 192
#define NBLK 64                        // 8192 / 128 row/col blocks
#define NTRI (NBLK * (NBLK + 1) / 2)   // 2080 upper-tri blocks (2080 = 8*260)

typedef __attribute__((ext_vector_type(8))) short   short8;
typedef __attribute__((ext_vector_type(8))) __bf16  bf16x8;
typedef __attribute__((ext_vector_type(4))) float   f32x4;
typedef __attribute__((ext_vector_type(4))) float   f4;

// -------- fused prep (fp32->bf16 + row norms) and class member lists --------
__global__ void prep_build_kernel(const float* __restrict__ E,
                                  unsigned short* __restrict__ Ebf,
                                  float* __restrict__ sq,
                                  const long long* __restrict__ labels,
                                  int* __restrict__ cnt,
                                  int* __restrict__ members,
                                  int* __restrict__ pos,
                                  unsigned int* __restrict__ counter) {
  if (blockIdx.x == 0 && threadIdx.x == 0) *counter = 0u;  // replaces memset dispatch
  if (blockIdx.x < NPTS / 4) {
    const int row  = blockIdx.x * 4 + (threadIdx.x >> 6);
    const int lane = threadIdx.x & 63;
    const float* rp = E + (size_t)row * DF + lane * 8;
    f4 x0 = *reinterpret_cast<const f4*>(rp);
    f4 x1 = *reinterpret_cast<const f4*>(rp + 4);
    float x[8] = {x0.x, x0.y, x0.z, x0.w, x1.x, x1.y, x1.z, x1.w};
    float s = 0.f;
    short8 o;
#pragma unroll
    for (int j = 0; j < 8; ++j) {
      s += x[j] * x[j];
      uint32_t u = __float_as_uint(x[j]);
      u += 0x7FFFu + ((u >> 16) & 1u);   // round-to-nearest-even bf16
      o[j] = (short)(u >> 16);
    }
    *reinterpret_cast<short8*>(Ebf + (size_t)row * DF + lane * 8) = o;
#pragma unroll
    for (int d = 1; d < 64; d <<= 1) s += __shfl_xor(s, d);
    if (lane == 0) sq[row] = s;
  } else {
    // class member list: 4 waves, 2-pass (count, then offset write)
    const int c    = blockIdx.x - NPTS / 4;
    const int lane = threadIdx.x & 63;
    const int wv   = threadIdx.x >> 6;
    __shared__ int wcnt[4];
    int local = 0;
    for (int chunk = wv * 32; chunk < wv * 32 + 32; ++chunk) {
      const int lab = (int)labels[chunk * 64 + lane];
      local += __popcll(__ballot(lab == c));
    }
    if (lane == 0) wcnt[wv] = local;
    __syncthreads();
    int base = 0, total = 0;
#pragma unroll
    for (int w = 0; w < 4; ++w) {
      if (w < wv) base += wcnt[w];
      total += wcnt[w];
    }
    for (int chunk = wv * 32; chunk < wv * 32 + 32; ++chunk) {
      const int idx = chunk * 64 + lane;
      const int lab = (int)labels[idx];
      const unsigned long long mask = __ballot(lab == c);
      if (lab == c) {
        const int prefix = __popcll(mask & ((1ull << lane) - 1ull));
        if (base + prefix < MAXM) {
          members[c * MAXM + base + prefix] = idx;
          pos[idx] = base + prefix;
        }
      }
      base += __popcll(mask);
    }
    if (wv == 0 && lane == 0) cnt[c] = (total < MAXM) ? total : MAXM;
  }
}

// ---------------- main: bf16 MFMA Gram + fused masked partial LSE ------------
// R11/R13 champion body. Register-bucket change: stream bfv one fragment at a
// time (af[4] preloaded) so total regs fit the <=128 bucket (m69 occupancy
// quantization: waves/SIMD steps at 64/128/256 total regs). launch_bounds
// (256,4) forces the allocator to the 128-reg budget -> 4 blocks/CU.
__global__ __launch_bounds__(256, 4)
void gram_lse_kernel(const unsigned short* __restrict__ Ebf,
                     const float* __restrict__ sq,
                     const long long* __restrict__ labels,
                     const int* __restrict__ pos,
                     float* __restrict__ Pm, float* __restrict__ Ps,
                     float* __restrict__ pairD) {
  __shared__ unsigned short As[128 * 64];   // 16 KiB, XOR-swizzled 16B chunks
  __shared__ unsigned short Bs[128 * 64];   // 16 KiB

  // XCD-chunked bijection on [0, NTRI)  (NTRI % 8 == 0)
  const int j = ((int)blockIdx.x & 7) * (NTRI / 8) + ((int)blockIdx.x >> 3);

  // super-tile-major decode (bijective over the 2080 upper-tri tiles)
  int biy, bix;
  if (j < 1536) {                     // 6 off-diag 16x16 squares
    const int s  = j >> 8;            // (0,1),(0,2),(0,3),(1,2),(1,3),(2,3)
    const int sy = (s < 3) ? 0 : (s < 5 ? 1 : 2);
    const int sx = (s < 3) ? (s + 1) : (s < 5 ? (s - 1) : 3);
    const int w  = j & 255;
    biy = sy * 16 + (w >> 4);
    bix = sx * 16 + (w & 15);
  } else {                            // 4 diagonal triangles (136 tiles each)
    int j2 = j - 1536;                // 0..543
    const int d = j2 / 136;
    int w = j2 - d * 136;
    int ty = 0;
    while (w >= 16 - ty) { w -= 16 - ty; ++ty; }
    biy = d * 16 + ty;
    bix = d * 16 + ty + w;
  }

  const int tid  = threadIdx.x;
  const int lane = tid & 63;
  const int wv   = tid >> 6;
  const int wr   = wv >> 1, wc = wv & 1;
  const int brow = biy * 128;
  const int bcol = bix * 128;

  const int srow   = lane >> 3;            // staging: row within 8-row group
  const int schunk = (lane & 7) ^ srow;    // pre-swizzled source chunk

  const int l15 = lane & 15;
  const int kg  = lane >> 4;

  f32x4 acc[4][4];
#pragma unroll
  for (int m = 0; m < 4; ++m)
#pragma unroll
    for (int n = 0; n < 4; ++n) acc[m][n] = (f32x4)0.f;

  for (int t = 0; t < DF / 64; ++t) {
    if (t) __syncthreads();                // prev iter's ds_reads are done
    const int kt = t * 64;
#pragma unroll
    for (int i = 0; i < 4; ++i) {
      const int q = wv * 4 + i;            // 1 KiB instruction q covers 8 rows
      const size_t goffA = (size_t)(brow + q * 8 + srow) * DF + kt + schunk * 8;
      const size_t goffB = (size_t)(bcol + q * 8 + srow) * DF + kt + schunk * 8;
      __builtin_amdgcn_global_load_lds(
          (const __attribute__((address_space(1))) void*)(Ebf + goffA),
          (__attribute__((address_space(3))) void*)(As + q * 512), 16, 0, 0);
      __builtin_amdgcn_global_load_lds(
          (const __attribute__((address_space(1))) void*)(Ebf + goffB),
          (__attribute__((address_space(3))) void*)(Bs + q * 512), 16, 0, 0);
    }
    __syncthreads();                       // drains vmcnt -> tile valid

#pragma unroll
    for (int s = 0; s < 2; ++s) {
      // preload A fragments (16 VGPR); stream B fragments one at a time
      bf16x8 af[4];
#pragma unroll
      for (int m = 0; m < 4; ++m) {
        const int r    = wr * 64 + m * 16 + l15;
        const int slot = (s * 4 + kg) ^ (r & 7);
        af[m] = *reinterpret_cast<const bf16x8*>(&As[r * 64 + slot * 8]);
      }
#pragma unroll
      for (int n = 0; n < 4; ++n) {
        const int r    = wc * 64 + n * 16 + l15;
        const int slot = (s * 4 + kg) ^ (r & 7);
        const bf16x8 bfv = *reinterpret_cast<const bf16x8*>(&Bs[r * 64 + slot * 8]);
#pragma unroll
        for (int m = 0; m < 4; ++m)
          acc[m][n] = __builtin_amdgcn_mfma_f32_16x16x32_bf16(af[m], bfv, acc[m][n], 0, 0, 0);
      }
    }
  }

  // ---- epilogue pass 1: d = sq_i + sq_j - 2g; same-class upper pairs ->
  //      pairD scatter; mask (stored back into acc); per-row partial LSE.
  float sqc[4]; int labc[4], gc[4];
#pragma unroll
  for (int n = 0; n < 4; ++n) {
    gc[n]   = bcol + wc * 64 + n * 16 + l15;
    sqc[n]  = sq[gc[n]];
    labc[n] = (int)labels[gc[n]];
  }
  const int pcol = bix * 2 + wc;           // row-side partial slot
#pragma unroll
  for (int m = 0; m < 4; ++m) {
#pragma unroll
    for (int reg = 0; reg < 4; ++reg) {
      const int grow = brow + wr * 64 + m * 16 + kg * 4 + reg;
      const float sqr = sq[grow];
      const int labr = (int)labels[grow];
      float dv[4];
      float mx = -3.0e38f;
#pragma unroll
      for (int n = 0; n < 4; ++n) {
        const float g = acc[m][n][reg];
        const float d = sqr + sqc[n] - 2.0f * g;
        const bool same = (labr == labc[n]);
        if (same && grow < gc[n]) {        // rare: load pos lazily (reg relief)
          const int p = pos[gc[n]];
          if ((unsigned)p < MAXM)
            pairD[(size_t)grow * MAXM + p] = d;   // exactly-once per pair
        }
        const float v = same ? -3.0e38f : d;
        dv[n] = v;
        acc[m][n][reg] = v;                // keep masked distance for pass 2
        mx = fmaxf(mx, v);
      }
#pragma unroll
      for (int o = 1; o < 16; o <<= 1) mx = fmaxf(mx, __shfl_xor(mx, o));
      float se = 0.f;
#pragma unroll
      for (int n = 0; n < 4; ++n)
        se += (dv[n] > -2.9e38f) ? __expf(dv[n] - mx) : 0.f;
#pragma unroll
      for (int o = 1; o < 16; o <<= 1) se += __shfl_xor(se, o);
      if (l15 == 0) {
        Pm[(size_t)grow * 128 + pcol] = mx;
        Ps[(size_t)grow * 128 + pcol] = se;
      }
    }
  }

  // ---- epilogue pass 2 (off-diagonal only): transpose-side partials.
  if (biy != bix) {
    const int tpcol = biy * 2 + wr;        // partial slot indexed by row-block half
#pragma unroll
    for (int n = 0; n < 4; ++n) {
      float tm = -3.0e38f;
#pragma unroll
      for (int m = 0; m < 4; ++m)
#pragma unroll
        for (int reg = 0; reg < 4; ++reg)
          tm = fmaxf(tm, acc[m][n][reg]);
      tm = fmaxf(tm, __shfl_xor(tm, 16));
      tm = fmaxf(tm, __shfl_xor(tm, 32));
      float ts = 0.f;
#pragma unroll
      for (int m = 0; m < 4; ++m)
#pragma unroll
        for (int reg = 0; reg < 4; ++reg) {
          const float v = acc[m][n][reg];
          ts += (v > -2.9e38f) ? __expf(v - tm) : 0.f;
        }
      ts += __shfl_xor(ts, 16);
      ts += __shfl_xor(ts, 32);
      if (kg == 0) {
        Pm[(size_t)gc[n] * 128 + tpcol] = tm;
        Ps[(size_t)gc[n] * 128 + tpcol] = ts;
      }
    }
  }
}

// -------- per-class pair losses (4 blocks/class) + last-block final ----------
__global__ void class_loss_final_kernel(const float* __restrict__ Pm,
                                        const float* __restrict__ Ps,
                                        const int* __restrict__ cnt,
                                        const int* __restrict__ members,
                                        const float* __restrict__ pairD,
                                        float* __restrict__ csum,
                                        unsigned int* __restrict__ counter,
                                        float* __restrict__ out) {
  const int c = blockIdx.x >> 2, h = blockIdx.x & 3;
  const int tid = threadIdx.x, wv = tid >> 6, lane = tid & 63;
  const int k = cnt[c];
  __shared__ float wsums[4];
  __shared__ int islast;
  const int* mem = members + c * MAXM;

  float accum = 0.f;
  for (int a = h * 4 + wv; a < k - 1; a += 16) {
    const int i = mem[a];
    // ln (log_negsum) for this anchor: combine its 128 partials in-wave
    const float m1 = Pm[(size_t)i * 128 + lane];
    const float m2 = Pm[(size_t)i * 128 + 64 + lane];
    const float s1 = Ps[(size_t)i * 128 + lane];
    const float s2 = Ps[(size_t)i * 128 + 64 + lane];
    float M = fmaxf(m1, m2);
#pragma unroll
    for (int o = 1; o < 64; o <<= 1) M = fmaxf(M, __shfl_xor(M, o));
    float S = s1 * __expf(m1 - M) + s2 * __expf(m2 - M);
#pragma unroll
    for (int o = 1; o < 64; o <<= 1) S += __shfl_xor(S, o);
    const float lna = M + __logf(S);       // butterfly: all lanes hold it

    const float* pd = pairD + (size_t)i * MAXM;
    for (int b = a + 1 + lane; b < k; b += 64) {
      const float z = lna - pd[b];
      accum += fmaxf(z, 0.f) + log1pf(__expf(-fabsf(z)));  // logaddexp(0,z)
    }
  }
#pragma unroll
  for (int o = 1; o < 64; o <<= 1) accum += __shfl_xor(accum, o);
  if (lane == 0) wsums[wv] = accum;
  __syncthreads();
  if (tid == 0) {
    csum[blockIdx.x] = wsums[0] + wsums[1] + wsums[2] + wsums[3];
    __threadfence();                        // publish csum before ticket
    const unsigned int t = atomicAdd(counter, 1u);
    islast = (t == (unsigned int)(gridDim.x - 1)) ? 1 : 0;
  }
  __syncthreads();

  if (islast) {
    __threadfence();                        // acquire all csum slots
    __shared__ float ssum[NCLS];
    __shared__ int   sval[NCLS];
    if (tid < NCLS) {
      const volatile float* vc = (const volatile float*)csum;
      const float cs = vc[tid * 4] + vc[tid * 4 + 1] +
                       vc[tid * 4 + 2] + vc[tid * 4 + 3];
      const int kk = cnt[tid];
      const float cc = (kk >= 2) ? 0.5f * (float)kk * (float)(kk - 1) : 0.f;
      const bool valid = cc > 0.f;
      ssum[tid] = valid ? cs / cc : 0.f;
      sval[tid] = valid ? 1 : 0;
    }
    __syncthreads();
    if (tid == 0) {
      float s = 0.f; int v = 0;
      for (int i = 0; i < NCLS; ++i) { s += ssum[i]; v += sval[i]; }
      out[0] = s / (float)v;
      out[1] = (float)v;
    }
  }
}

extern "C" void kernel_launch(void* const* d_in, const int* in_sizes, int n_in,
                              void* d_out, int out_size, void* d_ws, size_t ws_size,
                              hipStream_t stream) {
  const float* E = (const float*)d_in[0];
  const long long* labels = (const long long*)d_in[1];
  float* out = (float*)d_out;

  char* w = (char*)d_ws;
  auto carve = [&](size_t bytes) { char* p = w; w += (bytes + 255) & ~(size_t)255; return p; };
  unsigned short* Ebf = (unsigned short*)carve((size_t)NPTS * DF * 2); // 8 MiB
  float* sq      = (float*)carve((size_t)NPTS * 4);
  float* Pm      = (float*)carve((size_t)NPTS * 128 * 4);              // 4 MiB
  float* Ps      = (float*)carve((size_t)NPTS * 128 * 4);              // 4 MiB
  int*   cnt     = (int*)carve((size_t)NCLS * 4);
  int*   members = (int*)carve((size_t)NCLS * MAXM * 4);
  int*   pos     = (int*)carve((size_t)NPTS * 4);
  float* pairD   = (float*)carve((size_t)NPTS * MAXM * 4);             // 6.3 MiB
  float* csum    = (float*)carve((size_t)NCLS * 4 * 4);
  unsigned int* counter = (unsigned int*)carve(256);

  prep_build_kernel<<<NPTS / 4 + NCLS, 256, 0, stream>>>(E, Ebf, sq, labels, cnt,
                                                         members, pos, counter);
  gram_lse_kernel<<<NTRI, 256, 0, stream>>>(Ebf, sq, labels, pos, Pm, Ps, pairD);
  class_loss_final_kernel<<<NCLS * 4, 256, 0, stream>>>(Pm, Ps, cnt, members, pairD,
                                                        csum, counter, out);
}

// Round 19
// 112.305 us; speedup vs baseline: 1.0248x; 1.0248x over previous
//
#include <hip/hip_runtime.h>
#include <cstdint>
#include <cstddef>

#define NPTS 8192
#define DF   512
#define NCLS 128
#define MAXM 192
#define NBLK 64                        // 8192 / 128 row/col blocks
#define NTRI (NBLK * (NBLK + 1) / 2)   // 2080 upper-tri blocks (2080 = 8*260)

typedef __attribute__((ext_vector_type(8))) short   short8;
typedef __attribute__((ext_vector_type(8))) __bf16  bf16x8;
typedef __attribute__((ext_vector_type(4))) float   f32x4;
typedef __attribute__((ext_vector_type(4))) float   f4;

// -------- fused prep (fp32->bf16 + row norms) and class member lists --------
__global__ void prep_build_kernel(const float* __restrict__ E,
                                  unsigned short* __restrict__ Ebf,
                                  float* __restrict__ sq,
                                  const long long* __restrict__ labels,
                                  int* __restrict__ cnt,
                                  int* __restrict__ members,
                                  int* __restrict__ pos,
                                  unsigned int* __restrict__ counter) {
  if (blockIdx.x == 0 && threadIdx.x == 0) *counter = 0u;  // replaces memset dispatch
  if (blockIdx.x < NPTS / 4) {
    const int row  = blockIdx.x * 4 + (threadIdx.x >> 6);
    const int lane = threadIdx.x & 63;
    const float* rp = E + (size_t)row * DF + lane * 8;
    f4 x0 = *reinterpret_cast<const f4*>(rp);
    f4 x1 = *reinterpret_cast<const f4*>(rp + 4);
    float x[8] = {x0.x, x0.y, x0.z, x0.w, x1.x, x1.y, x1.z, x1.w};
    float s = 0.f;
    short8 o;
#pragma unroll
    for (int j = 0; j < 8; ++j) {
      s += x[j] * x[j];
      uint32_t u = __float_as_uint(x[j]);
      u += 0x7FFFu + ((u >> 16) & 1u);   // round-to-nearest-even bf16
      o[j] = (short)(u >> 16);
    }
    *reinterpret_cast<short8*>(Ebf + (size_t)row * DF + lane * 8) = o;
#pragma unroll
    for (int d = 1; d < 64; d <<= 1) s += __shfl_xor(s, d);
    if (lane == 0) sq[row] = s;
  } else {
    // class member list: 4 waves, 2-pass (count, then offset write)
    const int c    = blockIdx.x - NPTS / 4;
    const int lane = threadIdx.x & 63;
    const int wv   = threadIdx.x >> 6;
    __shared__ int wcnt[4];
    int local = 0;
    for (int chunk = wv * 32; chunk < wv * 32 + 32; ++chunk) {
      const int lab = (int)labels[chunk * 64 + lane];
      local += __popcll(__ballot(lab == c));
    }
    if (lane == 0) wcnt[wv] = local;
    __syncthreads();
    int base = 0, total = 0;
#pragma unroll
    for (int w = 0; w < 4; ++w) {
      if (w < wv) base += wcnt[w];
      total += wcnt[w];
    }
    for (int chunk = wv * 32; chunk < wv * 32 + 32; ++chunk) {
      const int idx = chunk * 64 + lane;
      const int lab = (int)labels[idx];
      const unsigned long long mask = __ballot(lab == c);
      if (lab == c) {
        const int prefix = __popcll(mask & ((1ull << lane) - 1ull));
        if (base + prefix < MAXM) {
          members[c * MAXM + base + prefix] = idx;
          pos[idx] = base + prefix;
        }
      }
      base += __popcll(mask);
    }
    if (wv == 0 && lane == 0) cnt[c] = (total < MAXM) ? total : MAXM;
  }
}

// ---------------- main: bf16 MFMA Gram + fused masked partial LSE ------------
// R14 champion body (grid decode, epilogue) with ONE structural change:
// BK=32 double-buffered K-loop (2 x 16 KiB = same 32 KiB LDS, same occupancy,
// same barrier/instruction totals) so stage(t+1) is issued BEFORE compute(t)
// and each barrier drain only pays residual load latency (T3-minimum recipe).
__global__ __launch_bounds__(256, 3)
void gram_lse_kernel(const unsigned short* __restrict__ Ebf,
                     const float* __restrict__ sq,
                     const long long* __restrict__ labels,
                     const int* __restrict__ pos,
                     float* __restrict__ Pm, float* __restrict__ Ps,
                     float* __restrict__ pairD) {
  __shared__ unsigned short SH[2 * 8192];   // 32 KiB: buf x (A 8KB | B 8KB)

  // XCD-chunked bijection on [0, NTRI)  (NTRI % 8 == 0)
  const int j = ((int)blockIdx.x & 7) * (NTRI / 8) + ((int)blockIdx.x >> 3);

  // super-tile-major decode (bijective over the 2080 upper-tri tiles)
  int biy, bix;
  if (j < 1536) {                     // 6 off-diag 16x16 squares
    const int s  = j >> 8;            // (0,1),(0,2),(0,3),(1,2),(1,3),(2,3)
    const int sy = (s < 3) ? 0 : (s < 5 ? 1 : 2);
    const int sx = (s < 3) ? (s + 1) : (s < 5 ? (s - 1) : 3);
    const int w  = j & 255;
    biy = sy * 16 + (w >> 4);
    bix = sx * 16 + (w & 15);
  } else {                            // 4 diagonal triangles (136 tiles each)
    int j2 = j - 1536;                // 0..543
    const int d = j2 / 136;
    int w = j2 - d * 136;
    int ty = 0;
    while (w >= 16 - ty) { w -= 16 - ty; ++ty; }
    biy = d * 16 + ty;
    bix = d * 16 + ty + w;
  }

  const int tid  = threadIdx.x;
  const int lane = tid & 63;
  const int wv   = tid >> 6;
  const int wr   = wv >> 1, wc = wv & 1;
  const int brow = biy * 128;
  const int bcol = bix * 128;

  // staging (BK=32): 4-lane groups cover one row's 64B (4 chunks of 16B)
  const int srow   = lane >> 2;            // row within 16-row group
  const int schunk = (lane & 3) ^ (srow & 3);  // pre-swizzled source chunk

  const int l15 = lane & 15;
  const int kg  = lane >> 4;

  f32x4 acc[4][4];
#pragma unroll
  for (int m = 0; m < 4; ++m)
#pragma unroll
    for (int n = 0; n < 4; ++n) acc[m][n] = (f32x4)0.f;

  auto stage = [&](int t) {
    unsigned short* Ab = SH + (t & 1) * 8192;
    unsigned short* Bb = Ab + 4096;
    const int kt = t * 32;
#pragma unroll
    for (int i = 0; i < 2; ++i) {
      const int q = wv * 2 + i;            // 8 groups x 16 rows = 128 rows
      const size_t goffA = (size_t)(brow + q * 16 + srow) * DF + kt + schunk * 8;
      const size_t goffB = (size_t)(bcol + q * 16 + srow) * DF + kt + schunk * 8;
      __builtin_amdgcn_global_load_lds(
          (const __attribute__((address_space(1))) void*)(Ebf + goffA),
          (__attribute__((address_space(3))) void*)(Ab + q * 512), 16, 0, 0);
      __builtin_amdgcn_global_load_lds(
          (const __attribute__((address_space(1))) void*)(Ebf + goffB),
          (__attribute__((address_space(3))) void*)(Bb + q * 512), 16, 0, 0);
    }
  };

  auto compute = [&](int t) {
    const unsigned short* Ab = SH + (t & 1) * 8192;
    const unsigned short* Bb = Ab + 4096;
    bf16x8 af[4], bfv[4];
#pragma unroll
    for (int m = 0; m < 4; ++m) {
      const int r    = wr * 64 + m * 16 + l15;
      const int slot = kg ^ (r & 3);
      af[m] = *reinterpret_cast<const bf16x8*>(&Ab[r * 32 + slot * 8]);
    }
#pragma unroll
    for (int n = 0; n < 4; ++n) {
      const int r    = wc * 64 + n * 16 + l15;
      const int slot = kg ^ (r & 3);
      bfv[n] = *reinterpret_cast<const bf16x8*>(&Bb[r * 32 + slot * 8]);
    }
#pragma unroll
    for (int m = 0; m < 4; ++m)
#pragma unroll
      for (int n = 0; n < 4; ++n)
        acc[m][n] = __builtin_amdgcn_mfma_f32_16x16x32_bf16(af[m], bfv[n], acc[m][n], 0, 0, 0);
  };

  stage(0);
  __syncthreads();                         // implicit vmcnt(0): tile 0 ready
  for (int t = 0; t < DF / 32; ++t) {      // 16 K-steps
    if (t < DF / 32 - 1) stage(t + 1);     // prefetch flies under compute(t)
    compute(t);
    __syncthreads();                       // drains: t+1 ready; buf[t&1] reads done
  }

  // ---- epilogue pass 1: d = sq_i + sq_j - 2g; same-class upper pairs ->
  //      pairD scatter; mask (stored back into acc); per-row partial LSE.
  float sqc[4]; int labc[4], gc[4], posc[4];
#pragma unroll
  for (int n = 0; n < 4; ++n) {
    gc[n]   = bcol + wc * 64 + n * 16 + l15;
    sqc[n]  = sq[gc[n]];
    labc[n] = (int)labels[gc[n]];
    posc[n] = pos[gc[n]];
  }
  const int pcol = bix * 2 + wc;           // row-side partial slot
#pragma unroll
  for (int m = 0; m < 4; ++m) {
#pragma unroll
    for (int reg = 0; reg < 4; ++reg) {
      const int grow = brow + wr * 64 + m * 16 + kg * 4 + reg;
      const float sqr = sq[grow];
      const int labr = (int)labels[grow];
      float dv[4];
      float mx = -3.0e38f;
#pragma unroll
      for (int n = 0; n < 4; ++n) {
        const float g = acc[m][n][reg];
        const float d = sqr + sqc[n] - 2.0f * g;
        const bool same = (labr == labc[n]);
        if (same && grow < gc[n] && (unsigned)posc[n] < MAXM)
          pairD[(size_t)grow * MAXM + posc[n]] = d;   // exactly-once per pair
        const float v = same ? -3.0e38f : d;
        dv[n] = v;
        acc[m][n][reg] = v;                // keep masked distance for pass 2
        mx = fmaxf(mx, v);
      }
#pragma unroll
      for (int o = 1; o < 16; o <<= 1) mx = fmaxf(mx, __shfl_xor(mx, o));
      float se = 0.f;
#pragma unroll
      for (int n = 0; n < 4; ++n)
        se += (dv[n] > -2.9e38f) ? __expf(dv[n] - mx) : 0.f;
#pragma unroll
      for (int o = 1; o < 16; o <<= 1) se += __shfl_xor(se, o);
      if (l15 == 0) {
        Pm[(size_t)grow * 128 + pcol] = mx;
        Ps[(size_t)grow * 128 + pcol] = se;
      }
    }
  }

  // ---- epilogue pass 2 (off-diagonal only): transpose-side partials.
  if (biy != bix) {
    const int tpcol = biy * 2 + wr;        // partial slot indexed by row-block half
#pragma unroll
    for (int n = 0; n < 4; ++n) {
      float tm = -3.0e38f;
#pragma unroll
      for (int m = 0; m < 4; ++m)
#pragma unroll
        for (int reg = 0; reg < 4; ++reg)
          tm = fmaxf(tm, acc[m][n][reg]);
      tm = fmaxf(tm, __shfl_xor(tm, 16));
      tm = fmaxf(tm, __shfl_xor(tm, 32));
      float ts = 0.f;
#pragma unroll
      for (int m = 0; m < 4; ++m)
#pragma unroll
        for (int reg = 0; reg < 4; ++reg) {
          const float v = acc[m][n][reg];
          ts += (v > -2.9e38f) ? __expf(v - tm) : 0.f;
        }
      ts += __shfl_xor(ts, 16);
      ts += __shfl_xor(ts, 32);
      if (kg == 0) {
        Pm[(size_t)gc[n] * 128 + tpcol] = tm;
        Ps[(size_t)gc[n] * 128 + tpcol] = ts;
      }
    }
  }
}

// -------- per-class pair losses (4 blocks/class) + last-block final ----------
__global__ void class_loss_final_kernel(const float* __restrict__ Pm,
                                        const float* __restrict__ Ps,
                                        const int* __restrict__ cnt,
                                        const int* __restrict__ members,
                                        const float* __restrict__ pairD,
                                        float* __restrict__ csum,
                                        unsigned int* __restrict__ counter,
                                        float* __restrict__ out) {
  const int c = blockIdx.x >> 2, h = blockIdx.x & 3;
  const int tid = threadIdx.x, wv = tid >> 6, lane = tid & 63;
  const int k = cnt[c];
  __shared__ float wsums[4];
  __shared__ int islast;
  const int* mem = members + c * MAXM;

  float accum = 0.f;
  for (int a = h * 4 + wv; a < k - 1; a += 16) {
    const int i = mem[a];
    // ln (log_negsum) for this anchor: combine its 128 partials in-wave
    const float m1 = Pm[(size_t)i * 128 + lane];
    const float m2 = Pm[(size_t)i * 128 + 64 + lane];
    const float s1 = Ps[(size_t)i * 128 + lane];
    const float s2 = Ps[(size_t)i * 128 + 64 + lane];
    float M = fmaxf(m1, m2);
#pragma unroll
    for (int o = 1; o < 64; o <<= 1) M = fmaxf(M, __shfl_xor(M, o));
    float S = s1 * __expf(m1 - M) + s2 * __expf(m2 - M);
#pragma unroll
    for (int o = 1; o < 64; o <<= 1) S += __shfl_xor(S, o);
    const float lna = M + __logf(S);       // butterfly: all lanes hold it

    const float* pd = pairD + (size_t)i * MAXM;
    for (int b = a + 1 + lane; b < k; b += 64) {
      const float z = lna - pd[b];
      accum += fmaxf(z, 0.f) + log1pf(__expf(-fabsf(z)));  // logaddexp(0,z)
    }
  }
#pragma unroll
  for (int o = 1; o < 64; o <<= 1) accum += __shfl_xor(accum, o);
  if (lane == 0) wsums[wv] = accum;
  __syncthreads();
  if (tid == 0) {
    csum[blockIdx.x] = wsums[0] + wsums[1] + wsums[2] + wsums[3];
    __threadfence();                        // publish csum before ticket
    const unsigned int t = atomicAdd(counter, 1u);
    islast = (t == (unsigned int)(gridDim.x - 1)) ? 1 : 0;
  }
  __syncthreads();

  if (islast) {
    __threadfence();                        // acquire all csum slots
    __shared__ float ssum[NCLS];
    __shared__ int   sval[NCLS];
    if (tid < NCLS) {
      const volatile float* vc = (const volatile float*)csum;
      const float cs = vc[tid * 4] + vc[tid * 4 + 1] +
                       vc[tid * 4 + 2] + vc[tid * 4 + 3];
      const int kk = cnt[tid];
      const float cc = (kk >= 2) ? 0.5f * (float)kk * (float)(kk - 1) : 0.f;
      const bool valid = cc > 0.f;
      ssum[tid] = valid ? cs / cc : 0.f;
      sval[tid] = valid ? 1 : 0;
    }
    __syncthreads();
    if (tid == 0) {
      float s = 0.f; int v = 0;
      for (int i = 0; i < NCLS; ++i) { s += ssum[i]; v += sval[i]; }
      out[0] = s / (float)v;
      out[1] = (float)v;
    }
  }
}

extern "C" void kernel_launch(void* const* d_in, const int* in_sizes, int n_in,
                              void* d_out, int out_size, void* d_ws, size_t ws_size,
                              hipStream_t stream) {
  const float* E = (const float*)d_in[0];
  const long long* labels = (const long long*)d_in[1];
  float* out = (float*)d_out;

  char* w = (char*)d_ws;
  auto carve = [&](size_t bytes) { char* p = w; w += (bytes + 255) & ~(size_t)255; return p; };
  unsigned short* Ebf = (unsigned short*)carve((size_t)NPTS * DF * 2); // 8 MiB
  float* sq      = (float*)carve((size_t)NPTS * 4);
  float* Pm      = (float*)carve((size_t)NPTS * 128 * 4);              // 4 MiB
  float* Ps      = (float*)carve((size_t)NPTS * 128 * 4);              // 4 MiB
  int*   cnt     = (int*)carve((size_t)NCLS * 4);
  int*   members = (int*)carve((size_t)NCLS * MAXM * 4);
  int*   pos     = (int*)carve((size_t)NPTS * 4);
  float* pairD   = (float*)carve((size_t)NPTS * MAXM * 4);             // 6.3 MiB
  float* csum    = (float*)carve((size_t)NCLS * 4 * 4);
  unsigned int* counter = (unsigned int*)carve(256);

  prep_build_kernel<<<NPTS / 4 + NCLS, 256, 0, stream>>>(E, Ebf, sq, labels, cnt,
                                                         members, pos, counter);
  gram_lse_kernel<<<NTRI, 256, 0, stream>>>(Ebf, sq, labels, pos, Pm, Ps, pairD);
  class_loss_final_kernel<<<NCLS * 4, 256, 0, stream>>>(Pm, Ps, cnt, members, pairD,
                                                        csum, counter, out);
}